// Round 1
// baseline (1832.642 us; speedup 1.0000x reference)
//
#include <hip/hip_runtime.h>

// PoolAggregator: GraphSAGE maxpool aggregator, fully fused.
//   x = neigh[N,K,F] @ Wt[F,T] + bt          (81.9 GFLOP, dominant)
//   bn1 (train) over [N*K, T]; max over K    -> fused: track max/min_k(x) + column sums
//   pooled @ Wn ; self @ Ws ; concat ; bn2 ; relu
// BN is per-column monotone affine => pool(BN(x)) = a*max(x)+c (a>=0) else a*min(x)+c.
// The [1.25M,256] intermediate never hits HBM.

#define N_NODES 50000
#define KN 25
#define FIN 128
#define TD 256
#define OUTD 128
#define BN_EPS 1e-3f
#define NPB 4        // nodes per block in K1
#define NB2 16       // nodes per block in K4/K6
#define NSLOTS 64    // atomic slot copies for column stats (cuts contention 64x)

// ---------------- K1: GEMM1 + max/min over k + BN1 column stats ----------------
__global__ __launch_bounds__(256) void k1_gemm_pool(
    const float* __restrict__ neigh, const float* __restrict__ Wt,
    const float* __restrict__ bt, float* __restrict__ nmax,
    float* __restrict__ nmin, float* __restrict__ s1sum, float* __restrict__ s1sq)
{
    __shared__ float shA[NPB * KN * FIN];          // 51.2 KB
    const int tid = threadIdx.x;
    const int n0 = blockIdx.x * NPB;

    // stage 4 nodes of neigh (contiguous 12800 floats) as float4
    {
        const float4* src = (const float4*)(neigh + (size_t)n0 * KN * FIN);
        float4* dst = (float4*)shA;
        #pragma unroll
        for (int i = 0; i < (NPB * KN * FIN / 4 + 255) / 256; ++i) {
            int idx = tid + i * 256;
            if (idx < NPB * KN * FIN / 4) dst[idx] = src[idx];
        }
    }
    __syncthreads();

    const int node = tid >> 6;          // wave id == node -> LDS reads wave-uniform
    const int c0 = (tid & 63) * 4;      // 4 contiguous output columns per thread
    float acc[KN][4];
    #pragma unroll
    for (int k = 0; k < KN; ++k) { acc[k][0] = 0.f; acc[k][1] = 0.f; acc[k][2] = 0.f; acc[k][3] = 0.f; }

    const float* A = shA + node * KN * FIN;
    for (int f = 0; f < FIN; f += 4) {
        const float4 w0 = *(const float4*)(Wt + (size_t)(f + 0) * TD + c0);
        const float4 w1 = *(const float4*)(Wt + (size_t)(f + 1) * TD + c0);
        const float4 w2 = *(const float4*)(Wt + (size_t)(f + 2) * TD + c0);
        const float4 w3 = *(const float4*)(Wt + (size_t)(f + 3) * TD + c0);
        #pragma unroll
        for (int k = 0; k < KN; ++k) {
            const float4 a = *(const float4*)(A + k * FIN + f);   // broadcast ds_read_b128
            acc[k][0] = fmaf(a.x, w0.x, fmaf(a.y, w1.x, fmaf(a.z, w2.x, fmaf(a.w, w3.x, acc[k][0]))));
            acc[k][1] = fmaf(a.x, w0.y, fmaf(a.y, w1.y, fmaf(a.z, w2.y, fmaf(a.w, w3.y, acc[k][1]))));
            acc[k][2] = fmaf(a.x, w0.z, fmaf(a.y, w1.z, fmaf(a.z, w2.z, fmaf(a.w, w3.z, acc[k][2]))));
            acc[k][3] = fmaf(a.x, w0.w, fmaf(a.y, w1.w, fmaf(a.z, w2.w, fmaf(a.w, w3.w, acc[k][3]))));
        }
    }

    // epilogue: +bt, then per-column max/min/sum/sumsq over the 25 k's
    const float4 btv = *(const float4*)(bt + c0);
    float bv[4] = { btv.x, btv.y, btv.z, btv.w };
    float mx[4], mn[4], sm[4], sq[4];
    #pragma unroll
    for (int j = 0; j < 4; ++j) { mx[j] = -3.4e38f; mn[j] = 3.4e38f; sm[j] = 0.f; sq[j] = 0.f; }
    #pragma unroll
    for (int k = 0; k < KN; ++k) {
        #pragma unroll
        for (int j = 0; j < 4; ++j) {
            const float x = acc[k][j] + bv[j];
            mx[j] = fmaxf(mx[j], x);
            mn[j] = fminf(mn[j], x);
            sm[j] += x;
            sq[j] = fmaf(x, x, sq[j]);
        }
    }
    const int gn = n0 + node;
    *(float4*)(nmax + (size_t)gn * TD + c0) = make_float4(mx[0], mx[1], mx[2], mx[3]);
    *(float4*)(nmin + (size_t)gn * TD + c0) = make_float4(mn[0], mn[1], mn[2], mn[3]);
    float* ss = s1sum + (size_t)(blockIdx.x & (NSLOTS - 1)) * TD + c0;
    float* sQ = s1sq  + (size_t)(blockIdx.x & (NSLOTS - 1)) * TD + c0;
    #pragma unroll
    for (int j = 0; j < 4; ++j) { atomicAdd(ss + j, sm[j]); atomicAdd(sQ + j, sq[j]); }
}

// ---------------- K2/K5: reduce slot stats -> BN affine coefficients ----------------
__global__ __launch_bounds__(256) void k_stats(
    const float* __restrict__ ssum, const float* __restrict__ ssq,
    const float* __restrict__ g, const float* __restrict__ b,
    float invM, float* __restrict__ a, float* __restrict__ cc)
{
    const int c = threadIdx.x;   // 256 columns
    float s = 0.f, q = 0.f;
    for (int j = 0; j < NSLOTS; ++j) { s += ssum[j * TD + c]; q += ssq[j * TD + c]; }
    const float mean = s * invM;
    const float var = q * invM - mean * mean;
    const float A = rsqrtf(var + BN_EPS) * g[c];
    a[c] = A;
    cc[c] = fmaf(-mean, A, b[c]);
}

// ---------------- K3: pooled = a1>=0 ? a1*max+c1 : a1*min+c1 (in-place over nmax) ----------------
__global__ __launch_bounds__(256) void k3_pool_affine(
    float* __restrict__ nmax, const float* __restrict__ nmin,
    const float* __restrict__ a1, const float* __restrict__ c1)
{
    const int idx = blockIdx.x * 256 + threadIdx.x;   // float4 index over N*TD/4
    const int c0 = (idx & 63) * 4;
    const float4 mx = ((const float4*)nmax)[idx];
    const float4 mn = ((const float4*)nmin)[idx];
    const float4 a = *(const float4*)(a1 + c0);
    const float4 c = *(const float4*)(c1 + c0);
    float4 r;
    r.x = (a.x >= 0.f) ? fmaf(a.x, mx.x, c.x) : fmaf(a.x, mn.x, c.x);
    r.y = (a.y >= 0.f) ? fmaf(a.y, mx.y, c.y) : fmaf(a.y, mn.y, c.y);
    r.z = (a.z >= 0.f) ? fmaf(a.z, mx.z, c.z) : fmaf(a.z, mn.z, c.z);
    r.w = (a.w >= 0.f) ? fmaf(a.w, mx.w, c.w) : fmaf(a.w, mn.w, c.w);
    ((float4*)nmax)[idx] = r;
}

// ---------------- K4 (stats) / K6 (write): [self@Ws | pooled@Wn], BN2 stats or BN2+relu ----------------
template <bool WRITE>
__global__ __launch_bounds__(256) void k46_gemm2(
    const float* __restrict__ selfn, const float* __restrict__ pooled,
    const float* __restrict__ Ws, const float* __restrict__ Wn,
    float* __restrict__ s2sum, float* __restrict__ s2sq,
    const float* __restrict__ a2, const float* __restrict__ c2,
    float* __restrict__ out)
{
    __shared__ float ssf[NB2 * FIN];   // 8 KB
    __shared__ float spl[NB2 * TD];    // 16 KB
    const int tid = threadIdx.x;
    const int n0 = blockIdx.x * NB2;
    {
        const float4* src = (const float4*)(selfn + (size_t)n0 * FIN);
        float4* dst = (float4*)ssf;
        for (int i = tid; i < NB2 * FIN / 4; i += 256) dst[i] = src[i];
        const float4* src2 = (const float4*)(pooled + (size_t)n0 * TD);
        float4* dst2 = (float4*)spl;
        for (int i = tid; i < NB2 * TD / 4; i += 256) dst2[i] = src2[i];
    }
    __syncthreads();

    float acc[NB2];
    #pragma unroll
    for (int i = 0; i < NB2; ++i) acc[i] = 0.f;
    const int c = tid;
    if (c < OUTD) {             // waves 0,1: self_out column c
        for (int f = 0; f < FIN; f += 4) {
            const float w0 = Ws[(size_t)(f + 0) * OUTD + c];
            const float w1 = Ws[(size_t)(f + 1) * OUTD + c];
            const float w2 = Ws[(size_t)(f + 2) * OUTD + c];
            const float w3 = Ws[(size_t)(f + 3) * OUTD + c];
            #pragma unroll
            for (int i = 0; i < NB2; ++i) {
                const float4 a = *(const float4*)(ssf + i * FIN + f);
                acc[i] = fmaf(a.x, w0, fmaf(a.y, w1, fmaf(a.z, w2, fmaf(a.w, w3, acc[i]))));
            }
        }
    } else {                    // waves 2,3: neigh_out column c-128
        const int cw = c - OUTD;
        for (int f = 0; f < TD; f += 4) {
            const float w0 = Wn[(size_t)(f + 0) * OUTD + cw];
            const float w1 = Wn[(size_t)(f + 1) * OUTD + cw];
            const float w2 = Wn[(size_t)(f + 2) * OUTD + cw];
            const float w3 = Wn[(size_t)(f + 3) * OUTD + cw];
            #pragma unroll
            for (int i = 0; i < NB2; ++i) {
                const float4 a = *(const float4*)(spl + i * TD + f);
                acc[i] = fmaf(a.x, w0, fmaf(a.y, w1, fmaf(a.z, w2, fmaf(a.w, w3, acc[i]))));
            }
        }
    }

    if (WRITE) {
        const float A = a2[c], C = c2[c];
        #pragma unroll
        for (int i = 0; i < NB2; ++i)
            out[(size_t)(n0 + i) * TD + c] = fmaxf(0.f, fmaf(A, acc[i], C));
    } else {
        float sm = 0.f, sq = 0.f;
        #pragma unroll
        for (int i = 0; i < NB2; ++i) { sm += acc[i]; sq = fmaf(acc[i], acc[i], sq); }
        atomicAdd(s2sum + (size_t)(blockIdx.x & (NSLOTS - 1)) * TD + c, sm);
        atomicAdd(s2sq  + (size_t)(blockIdx.x & (NSLOTS - 1)) * TD + c, sq);
    }
}

extern "C" void kernel_launch(void* const* d_in, const int* in_sizes, int n_in,
                              void* d_out, int out_size, void* d_ws, size_t ws_size,
                              hipStream_t stream) {
    const float* selfn = (const float*)d_in[0];
    const float* neigh = (const float*)d_in[1];
    // d_in[2] = len_adj_nodes: unused by the reference
    const float* Wt = (const float*)d_in[3];
    const float* bt = (const float*)d_in[4];
    const float* g1 = (const float*)d_in[5];
    const float* b1 = (const float*)d_in[6];
    const float* Wn = (const float*)d_in[7];
    const float* Ws = (const float*)d_in[8];
    const float* g2 = (const float*)d_in[9];
    const float* b2 = (const float*)d_in[10];
    float* out = (float*)d_out;

    // workspace layout (floats): nmax[N*T] | nmin[N*T] | 4 x slots[64*T] | a1,c1,a2,c2
    float* ws = (float*)d_ws;
    float* nmax = ws;
    float* nmin = nmax + (size_t)N_NODES * TD;
    float* s1sum = nmin + (size_t)N_NODES * TD;
    float* s1sq = s1sum + NSLOTS * TD;
    float* s2sum = s1sq + NSLOTS * TD;
    float* s2sq = s2sum + NSLOTS * TD;
    float* a1 = s2sq + NSLOTS * TD;
    float* c1 = a1 + TD;
    float* a2 = c1 + TD;
    float* c2 = a2 + TD;

    // zero the atomic slot arrays (ws is poisoned 0xAA before every launch)
    hipMemsetAsync(s1sum, 0, (size_t)4 * NSLOTS * TD * sizeof(float), stream);

    k1_gemm_pool<<<N_NODES / NPB, 256, 0, stream>>>(neigh, Wt, bt, nmax, nmin, s1sum, s1sq);
    k_stats<<<1, 256, 0, stream>>>(s1sum, s1sq, g1, b1, 1.f / (float)(N_NODES * KN), a1, c1);
    k3_pool_affine<<<N_NODES * TD / 4 / 256, 256, 0, stream>>>(nmax, nmin, a1, c1);
    k46_gemm2<false><<<N_NODES / NB2, 256, 0, stream>>>(selfn, nmax, Ws, Wn, s2sum, s2sq, a2, c2, out);
    k_stats<<<1, 256, 0, stream>>>(s2sum, s2sq, g2, b2, 1.f / (float)N_NODES, a2, c2);
    k46_gemm2<true><<<N_NODES / NB2, 256, 0, stream>>>(selfn, nmax, Ws, Wn, s2sum, s2sq, a2, c2, out);
}

// Round 2
// 994.980 us; speedup vs baseline: 1.8419x; 1.8419x over previous
//
#include <hip/hip_runtime.h>

// PoolAggregator fused, MFMA (bf16 in / f32 acc) version.
//   K1: x = neigh@Wt + bt, track per-node max/min over k (25 rows padded to 32)
//       plus BN1 column sums — the [1.25M,256] tensor never hits HBM.
//   k_stats: slot-reduce -> BN affine (a,c).  pool(BN(x)) = a>=0 ? a*max+c : a*min+c.
//   K2: [self@Ws | pooled@Wn] via MFMA, BN1-affine fused into A staging,
//       writes pre-BN Y to d_out + BN2 column sums.
//   k7: out = relu(a2*Y + c2) in place.

#define NN 50000
#define KN 25
#define FIN 128
#define TD 256
#define OUTD 128
#define BN_EPS 1e-3f
#define NSLOTS 64
#define K1_GRID 512
#define NGROUPS (NN / 2)   // 2 nodes per group

typedef float f32x4 __attribute__((ext_vector_type(4)));
typedef short bf16x8 __attribute__((ext_vector_type(8)));

__device__ __forceinline__ ushort f2bf(float f) {
    uint u = __builtin_bit_cast(uint, f);
    return (ushort)((u + 0x7FFFu + ((u >> 16) & 1u)) >> 16);
}
__device__ __forceinline__ uint pk2(float a, float b) {
    return (uint)f2bf(a) | ((uint)f2bf(b) << 16);
}

// ============ K1: GEMM1 + pool-prep + BN1 stats ============
// Block: 256 thr (4 waves), persistent. Group = 2 nodes = 50 real rows,
// padded to 64 (node g at padded rows 32g..32g+31; rows 25..31 are garbage,
// masked in epilogue — MFMA rows are independent so garbage can't leak).
// LDS 64 KB exactly: Wt staged bf16 [128][256] once, B-frags -> regs,
// then region reused as 2x double-buffered A [64 rows][136] bf16 (pad +8
// breaks the 256B-stride bank alias; frag b128 pattern lands min-conflict).
__global__ __launch_bounds__(256, 2) void k1_gemm_pool(
    const float* __restrict__ neigh, const float* __restrict__ Wt,
    const float* __restrict__ bt, float* __restrict__ nmax,
    float* __restrict__ nmin, float* __restrict__ s1sum, float* __restrict__ s1sq)
{
    __shared__ ushort lds[32768];   // 65536 B
    const int tid = threadIdx.x;
    const int wave = tid >> 6, lane = tid & 63;
    const int quad = lane >> 4, l16 = lane & 15;
    const int cbase = wave * 64;

    // ---- stage Wt -> LDS bf16, row-major [k][col] ----
    {
        const float4* w4 = (const float4*)Wt;     // 8192 float4
        #pragma unroll
        for (int i = 0; i < 32; ++i) {
            const int e = tid + i * 256;
            const int k = e >> 6, c4 = (e & 63) << 2;
            const float4 v = w4[e];
            uint* dst = (uint*)&lds[k * 256 + c4];
            dst[0] = pk2(v.x, v.y);
            dst[1] = pk2(v.z, v.w);
        }
    }
    __syncthreads();

    // ---- B-frags to regs: bf[nt][ks][j] = B[ks*32+quad*8+j][cbase+nt*16+l16] ----
    bf16x8 bf[4][4];
    #pragma unroll
    for (int nt = 0; nt < 4; ++nt) {
        const int col = cbase + nt * 16 + l16;
        #pragma unroll
        for (int ks = 0; ks < 4; ++ks) {
            #pragma unroll
            for (int j = 0; j < 8; ++j)
                bf[nt][ks][j] = (short)lds[(ks * 32 + quad * 8 + j) * 256 + col];
        }
    }
    __syncthreads();   // before A staging overwrites the B region

    float bv[4];
    #pragma unroll
    for (int n = 0; n < 4; ++n) bv[n] = bt[cbase + n * 16 + l16];

    float S[4] = {0.f, 0.f, 0.f, 0.f}, Q[4] = {0.f, 0.f, 0.f, 0.f};

    // ---- preload first group into buf 0 ----
    int g = blockIdx.x;
    {
        const float2* src = (const float2*)(neigh + (size_t)g * 6400);
        #pragma unroll
        for (int i = 0; i < 13; ++i) {
            const int idx = tid + i * 256;
            if (idx < 3200) {
                const float2 v = src[idx];
                const int r = idx >> 6;
                const int pr = r + (r >= 25 ? 7 : 0);   // node1 -> padded rows 32+
                *(uint*)&lds[pr * 136 + ((idx & 63) << 1)] = pk2(v.x, v.y);
            }
        }
    }
    __syncthreads();

    int cur = 0;
    for (; g < NGROUPS; g += K1_GRID) {
        const int gn = g + K1_GRID;
        // prefetch next group's A into regs (overlaps with MFMA below)
        float2 pre[13];
        if (gn < NGROUPS) {
            const float2* src = (const float2*)(neigh + (size_t)gn * 6400);
            #pragma unroll
            for (int i = 0; i < 13; ++i) {
                const int idx = tid + i * 256;
                if (idx < 3200) pre[i] = src[idx];
            }
        }
        // ---- MFMA: 4 m-tiles x 4 n-tiles x 4 k-slices ----
        const ushort* Ab = lds + cur * 8704;
        f32x4 acc[4][4];
        #pragma unroll
        for (int m = 0; m < 4; ++m)
            #pragma unroll
            for (int n = 0; n < 4; ++n)
                acc[m][n] = (f32x4){0.f, 0.f, 0.f, 0.f};
        #pragma unroll
        for (int m = 0; m < 4; ++m) {
            bf16x8 af[4];
            #pragma unroll
            for (int ks = 0; ks < 4; ++ks)
                af[ks] = *(const bf16x8*)&Ab[(m * 16 + l16) * 136 + ks * 32 + quad * 8];
            #pragma unroll
            for (int n = 0; n < 4; ++n)
                #pragma unroll
                for (int ks = 0; ks < 4; ++ks)
                    acc[m][n] = __builtin_amdgcn_mfma_f32_16x16x32_bf16(af[ks], bf[n][ks], acc[m][n], 0, 0, 0);
        }
        // ---- epilogue: per node (m-tiles {2g,2g+1}), mask padded rows ----
        // C layout: col = lane&15, row = quad*4 + reg (m89-verified).
        // m even: rows 0..15 all real. m odd: row 16+quad*4+i valid iff quad*4+i<9.
        #pragma unroll
        for (int gi = 0; gi < 2; ++gi) {
            const int node = g * 2 + gi;
            #pragma unroll
            for (int n = 0; n < 4; ++n) {
                float mx = -3.4e38f, mn = 3.4e38f;
                #pragma unroll
                for (int i = 0; i < 4; ++i) {
                    const float v = acc[2 * gi][n][i] + bv[n];
                    mx = fmaxf(mx, v); mn = fminf(mn, v);
                    S[n] += v; Q[n] = fmaf(v, v, Q[n]);
                }
                #pragma unroll
                for (int i = 0; i < 4; ++i) {
                    if (quad * 4 + i < 9) {
                        const float v = acc[2 * gi + 1][n][i] + bv[n];
                        mx = fmaxf(mx, v); mn = fminf(mn, v);
                        S[n] += v; Q[n] = fmaf(v, v, Q[n]);
                    }
                }
                mx = fmaxf(mx, __shfl_xor(mx, 16)); mx = fmaxf(mx, __shfl_xor(mx, 32));
                mn = fminf(mn, __shfl_xor(mn, 16)); mn = fminf(mn, __shfl_xor(mn, 32));
                if (lane < 16) {
                    const int o = node * TD + cbase + n * 16 + lane;
                    nmax[o] = mx; nmin[o] = mn;
                }
            }
        }
        // ---- write prefetched A into the other buffer ----
        if (gn < NGROUPS) {
            ushort* Aw = lds + (cur ^ 1) * 8704;
            #pragma unroll
            for (int i = 0; i < 13; ++i) {
                const int idx = tid + i * 256;
                if (idx < 3200) {
                    const int r = idx >> 6;
                    const int pr = r + (r >= 25 ? 7 : 0);
                    *(uint*)&Aw[pr * 136 + ((idx & 63) << 1)] = pk2(pre[i].x, pre[i].y);
                }
            }
        }
        __syncthreads();
        cur ^= 1;
    }
    // ---- flush BN1 stats (once per block) ----
    #pragma unroll
    for (int n = 0; n < 4; ++n) {
        float s = S[n]; s += __shfl_xor(s, 16); s += __shfl_xor(s, 32);
        float q = Q[n]; q += __shfl_xor(q, 16); q += __shfl_xor(q, 32);
        if (lane < 16) {
            const int col = cbase + n * 16 + lane;
            const int slot = blockIdx.x & (NSLOTS - 1);
            atomicAdd(&s1sum[slot * TD + col], s);
            atomicAdd(&s1sq[slot * TD + col], q);
        }
    }
}

// ============ slot stats -> BN affine coefficients ============
__global__ __launch_bounds__(256) void k_stats(
    const float* __restrict__ ssum, const float* __restrict__ ssq,
    const float* __restrict__ g, const float* __restrict__ b,
    float invM, float* __restrict__ a, float* __restrict__ cc)
{
    const int c = threadIdx.x;
    float s = 0.f, q = 0.f;
    for (int j = 0; j < NSLOTS; ++j) { s += ssum[j * TD + c]; q += ssq[j * TD + c]; }
    const float mean = s * invM;
    const float var = q * invM - mean * mean;
    const float A = rsqrtf(var + BN_EPS) * g[c];
    a[c] = A;
    cc[c] = fmaf(-mean, A, b[c]);
}

// ============ K2: [self@Ws | pooled@Wn] MFMA, Y (pre-BN2) -> d_out + stats ============
// Block: 64 rows, 4 waves. Waves 0,1: self GEMM (K=128); waves 2,3: pooled (K=256).
// Output col base = wave*64 (matches concat order). B-frags direct from global (L2).
__global__ __launch_bounds__(256, 2) void k2_gemm2(
    const float* __restrict__ selfn, const float* __restrict__ nmax,
    const float* __restrict__ nmin, const float* __restrict__ Ws,
    const float* __restrict__ Wn, const float* __restrict__ a1,
    const float* __restrict__ c1, float* __restrict__ Y,
    float* __restrict__ s2sum, float* __restrict__ s2sq)
{
    __shared__ ushort lds[25600];   // As[64][136] @0 (17408B), Ap[64][264] @8704 (33792B)
    const int tid = threadIdx.x;
    const int wave = tid >> 6, lane = tid & 63;
    const int quad = lane >> 4, l16 = lane & 15;
    const int R0 = blockIdx.x * 64;

    // stage self -> As (bf16)
    {
        const float4* s4 = (const float4*)selfn;
        #pragma unroll
        for (int i = 0; i < 8; ++i) {
            const int e = tid + i * 256;          // < 2048
            const int r = e >> 5, k4 = e & 31;
            const int gr = R0 + r;
            const float4 v = (gr < NN) ? s4[(size_t)gr * 32 + k4] : make_float4(0.f, 0.f, 0.f, 0.f);
            uint* dst = (uint*)&lds[r * 136 + (k4 << 2)];
            dst[0] = pk2(v.x, v.y);
            dst[1] = pk2(v.z, v.w);
        }
    }
    // stage pooled -> Ap: pooled = a1>=0 ? a1*max+c1 : a1*min+c1, to bf16
    {
        const float4* mx4 = (const float4*)nmax;
        const float4* mn4 = (const float4*)nmin;
        const float4* a4p = (const float4*)a1;
        const float4* c4p = (const float4*)c1;
        #pragma unroll
        for (int i = 0; i < 16; ++i) {
            const int e = tid + i * 256;          // < 4096
            const int r = e >> 6, c4 = e & 63;
            const int gr = R0 + r;
            const float4 vx = (gr < NN) ? mx4[(size_t)gr * 64 + c4] : make_float4(0.f, 0.f, 0.f, 0.f);
            const float4 vn = (gr < NN) ? mn4[(size_t)gr * 64 + c4] : make_float4(0.f, 0.f, 0.f, 0.f);
            const float4 a = a4p[c4], c = c4p[c4];
            const float p0 = (a.x >= 0.f) ? fmaf(a.x, vx.x, c.x) : fmaf(a.x, vn.x, c.x);
            const float p1 = (a.y >= 0.f) ? fmaf(a.y, vx.y, c.y) : fmaf(a.y, vn.y, c.y);
            const float p2 = (a.z >= 0.f) ? fmaf(a.z, vx.z, c.z) : fmaf(a.z, vn.z, c.z);
            const float p3 = (a.w >= 0.f) ? fmaf(a.w, vx.w, c.w) : fmaf(a.w, vn.w, c.w);
            uint* dst = (uint*)&lds[8704 + r * 264 + (c4 << 2)];
            dst[0] = pk2(p0, p1);
            dst[1] = pk2(p2, p3);
        }
    }
    __syncthreads();

    f32x4 acc[4][4];
    #pragma unroll
    for (int m = 0; m < 4; ++m)
        #pragma unroll
        for (int n = 0; n < 4; ++n)
            acc[m][n] = (f32x4){0.f, 0.f, 0.f, 0.f};

    if (wave < 2) {
        const int cb = wave * 64;
        bf16x8 bfr[4][4];
        #pragma unroll
        for (int nt = 0; nt < 4; ++nt)
            #pragma unroll
            for (int ks = 0; ks < 4; ++ks)
                #pragma unroll
                for (int j = 0; j < 8; ++j)
                    bfr[nt][ks][j] = (short)f2bf(Ws[(ks * 32 + quad * 8 + j) * OUTD + cb + nt * 16 + l16]);
        #pragma unroll
        for (int m = 0; m < 4; ++m) {
            bf16x8 af[4];
            #pragma unroll
            for (int ks = 0; ks < 4; ++ks)
                af[ks] = *(const bf16x8*)&lds[(m * 16 + l16) * 136 + ks * 32 + quad * 8];
            #pragma unroll
            for (int nt = 0; nt < 4; ++nt)
                #pragma unroll
                for (int ks = 0; ks < 4; ++ks)
                    acc[m][nt] = __builtin_amdgcn_mfma_f32_16x16x32_bf16(af[ks], bfr[nt][ks], acc[m][nt], 0, 0, 0);
        }
    } else {
        const int cb = (wave - 2) * 64;
        bf16x8 bfr[4][8];
        #pragma unroll
        for (int nt = 0; nt < 4; ++nt)
            #pragma unroll
            for (int ks = 0; ks < 8; ++ks)
                #pragma unroll
                for (int j = 0; j < 8; ++j)
                    bfr[nt][ks][j] = (short)f2bf(Wn[(ks * 32 + quad * 8 + j) * OUTD + cb + nt * 16 + l16]);
        #pragma unroll
        for (int m = 0; m < 4; ++m) {
            bf16x8 af[8];
            #pragma unroll
            for (int ks = 0; ks < 8; ++ks)
                af[ks] = *(const bf16x8*)&lds[8704 + (m * 16 + l16) * 264 + ks * 32 + quad * 8];
            #pragma unroll
            for (int nt = 0; nt < 4; ++nt)
                #pragma unroll
                for (int ks = 0; ks < 8; ++ks)
                    acc[m][nt] = __builtin_amdgcn_mfma_f32_16x16x32_bf16(af[ks], bfr[nt][ks], acc[m][nt], 0, 0, 0);
        }
    }

    // epilogue: Y (pre-BN2) + column stats
    const int colb = wave * 64;
    float S[4] = {0.f, 0.f, 0.f, 0.f}, Q[4] = {0.f, 0.f, 0.f, 0.f};
    #pragma unroll
    for (int m = 0; m < 4; ++m) {
        #pragma unroll
        for (int nt = 0; nt < 4; ++nt) {
            #pragma unroll
            for (int i = 0; i < 4; ++i) {
                const int row = R0 + m * 16 + quad * 4 + i;
                const float v = acc[m][nt][i];
                if (row < NN) {
                    Y[(size_t)row * TD + colb + nt * 16 + l16] = v;
                    S[nt] += v;
                    Q[nt] = fmaf(v, v, Q[nt]);
                }
            }
        }
    }
    #pragma unroll
    for (int nt = 0; nt < 4; ++nt) {
        float s = S[nt]; s += __shfl_xor(s, 16); s += __shfl_xor(s, 32);
        float q = Q[nt]; q += __shfl_xor(q, 16); q += __shfl_xor(q, 32);
        if (lane < 16) {
            const int col = colb + nt * 16 + lane;
            const int slot = blockIdx.x & (NSLOTS - 1);
            atomicAdd(&s2sum[slot * TD + col], s);
            atomicAdd(&s2sq[slot * TD + col], q);
        }
    }
}

// ============ K7: out = relu(a2*Y + c2), in place on d_out ============
__global__ __launch_bounds__(256) void k7_bn_relu(
    float* __restrict__ out, const float* __restrict__ a2, const float* __restrict__ c2)
{
    const int idx = blockIdx.x * 256 + threadIdx.x;   // float4 index, N*TD/4
    const int c4 = idx & 63;
    float4 y = ((const float4*)out)[idx];
    const float4 a = ((const float4*)a2)[c4];
    const float4 c = ((const float4*)c2)[c4];
    y.x = fmaxf(0.f, fmaf(a.x, y.x, c.x));
    y.y = fmaxf(0.f, fmaf(a.y, y.y, c.y));
    y.z = fmaxf(0.f, fmaf(a.z, y.z, c.z));
    y.w = fmaxf(0.f, fmaf(a.w, y.w, c.w));
    ((float4*)out)[idx] = y;
}

extern "C" void kernel_launch(void* const* d_in, const int* in_sizes, int n_in,
                              void* d_out, int out_size, void* d_ws, size_t ws_size,
                              hipStream_t stream) {
    const float* selfn = (const float*)d_in[0];
    const float* neigh = (const float*)d_in[1];
    // d_in[2] = len_adj_nodes: unused by the reference
    const float* Wt = (const float*)d_in[3];
    const float* bt = (const float*)d_in[4];
    const float* g1 = (const float*)d_in[5];
    const float* b1 = (const float*)d_in[6];
    const float* Wn = (const float*)d_in[7];
    const float* Ws = (const float*)d_in[8];
    const float* g2 = (const float*)d_in[9];
    const float* b2 = (const float*)d_in[10];
    float* out = (float*)d_out;

    // ws layout (floats): nmax[N*T] | nmin[N*T] | s1sum,s1sq,s2sum,s2sq [64*T each] | a1,c1,a2,c2
    float* ws = (float*)d_ws;
    float* nmax = ws;
    float* nmin = nmax + (size_t)NN * TD;
    float* s1sum = nmin + (size_t)NN * TD;
    float* s1sq = s1sum + NSLOTS * TD;
    float* s2sum = s1sq + NSLOTS * TD;
    float* s2sq = s2sum + NSLOTS * TD;
    float* a1 = s2sq + NSLOTS * TD;
    float* c1 = a1 + TD;
    float* a2 = c1 + TD;
    float* c2 = a2 + TD;

    hipMemsetAsync(s1sum, 0, (size_t)4 * NSLOTS * TD * sizeof(float), stream);

    k1_gemm_pool<<<K1_GRID, 256, 0, stream>>>(neigh, Wt, bt, nmax, nmin, s1sum, s1sq);
    k_stats<<<1, 256, 0, stream>>>(s1sum, s1sq, g1, b1, 1.f / (float)(NN * KN), a1, c1);
    k2_gemm2<<<(NN + 63) / 64, 256, 0, stream>>>(selfn, nmax, nmin, Ws, Wn, a1, c1, out, s2sum, s2sq);
    k_stats<<<1, 256, 0, stream>>>(s2sum, s2sq, g2, b2, 1.f / (float)NN, a2, c2);
    k7_bn_relu<<<NN * TD / 4 / 256, 256, 0, stream>>>(out, a2, c2);
}